// Round 5
// baseline (280.431 us; speedup 1.0000x reference)
//
#include <hip/hip_runtime.h>
#include <hip/hip_bf16.h>
#include <stdint.h>

#define T_SEQ 4096
#define DIMX 1024
#define NH 16
#define HD 64
#define DLAT 256

typedef __bf16 bf16x8 __attribute__((ext_vector_type(8)));
typedef __bf16 bf16x4 __attribute__((ext_vector_type(4)));
typedef float floatx4 __attribute__((ext_vector_type(4)));

#define MFMA(a, b, c) __builtin_amdgcn_mfma_f32_16x16x32_bf16(a, b, c, 0, 0, 0)

__device__ inline void gload_lds16(const __bf16* g, __bf16* l) {
  __builtin_amdgcn_global_load_lds(
      (const __attribute__((address_space(1))) uint32_t*)g,
      (__attribute__((address_space(3))) uint32_t*)l, 16, 0, 0);
}

// ---------- prep: x f32->bf16 convert + 5 weight transposes (round-8) -------
__global__ __launch_bounds__(256) void prep_kernel(
    const float* __restrict__ x, const float* __restrict__ wdkv,
    const float* __restrict__ wuk, const float* __restrict__ wuv,
    const float* __restrict__ wuq, const float* __restrict__ wo,
    __bf16* __restrict__ x_bf, __bf16* __restrict__ wt_dkv,
    __bf16* __restrict__ wt_uk, __bf16* __restrict__ wt_uv,
    __bf16* __restrict__ wt_uq, __bf16* __restrict__ wt_o) {
  int id = blockIdx.x;
  if (id < 2048) {
    int i = id * 256 + threadIdx.x;
    const float4* p = (const float4*)x;
    float4 a = p[2 * i], b = p[2 * i + 1];
    bf16x8 r = {(__bf16)a.x, (__bf16)a.y, (__bf16)a.z, (__bf16)a.w,
                (__bf16)b.x, (__bf16)b.y, (__bf16)b.z, (__bf16)b.w};
    *(bf16x8*)(x_bf + 8 * (size_t)i) = r;
    return;
  }
  int t = id - 2048;
  const float* in;
  __bf16* out;
  int R, C, lt;
  if (t < 64)       { in = wdkv; out = wt_dkv; R = 1024; C = 256;  lt = t; }
  else if (t < 128) { in = wuk;  out = wt_uk;  R = 256;  C = 1024; lt = t - 64; }
  else if (t < 192) { in = wuv;  out = wt_uv;  R = 256;  C = 1024; lt = t - 128; }
  else if (t < 448) { in = wuq;  out = wt_uq;  R = 1024; C = 1024; lt = t - 192; }
  else              { in = wo;   out = wt_o;   R = 1024; C = 1024; lt = t - 448; }
  __shared__ __bf16 tls[64][65];
  int tpr = C >> 6;
  int r0 = (lt / tpr) * 64, c0 = (lt % tpr) * 64;
  int tid = threadIdx.x;
#pragma unroll
  for (int i = 0; i < 16; i++) {
    int idx = tid + i * 256;
    int r = idx >> 6, c = idx & 63;
    tls[r][c] = (__bf16)in[(size_t)(r0 + r) * C + c0 + c];
  }
  __syncthreads();
#pragma unroll
  for (int i = 0; i < 16; i++) {
    int idx = tid + i * 256;
    int rr = idx & 63, cc = idx >> 6;
    out[(size_t)(c0 + cc) * R + r0 + rr] = tls[rr][cc];
  }
}

// ======== 128x128 GEMM, BK=64 via two independent BK=32 buffers =============
#define BUFE 4096  // 128*32

// ---------- gemm_a128: ckv = x@Wdkv' (bx<2), q = s*x@Wuq' (bx>=2) -----------
// q scale folds 1/8 (softmax scale) * log2(e) so attn can use exp2.
__global__ __launch_bounds__(256) void gemm_a128(const __bf16* __restrict__ A,
                                                 const __bf16* __restrict__ B1,
                                                 const __bf16* __restrict__ B2,
                                                 __bf16* __restrict__ C1,
                                                 __bf16* __restrict__ C2) {
  __shared__ __attribute__((aligned(16))) __bf16 Al[2][BUFE];
  __shared__ __attribute__((aligned(16))) __bf16 Bl[2][BUFE];
  int tid = threadIdx.x;
  int w = tid >> 6, lane = tid & 63;
  int quad = lane >> 4, l16 = lane & 15;
  int mw = w & 1, nw = w >> 1;
  int bx = blockIdx.x, m0 = blockIdx.y * 128;
  const __bf16* Bt;
  __bf16* C;
  int n0, N;
  float sc;
  if (bx < 2) { Bt = B1; C = C1; n0 = bx * 128; N = DLAT; sc = 1.0f; }
  else        { Bt = B2; C = C2; n0 = (bx - 2) * 128; N = DIMX;
                sc = 0.125f * 1.44269504088896340736f; }
  const int K = DIMX;
  int arow = w * 32 + (lane >> 2), acol = (lane & 3) << 3;

  floatx4 acc[4][4];
#pragma unroll
  for (int i = 0; i < 4; i++)
#pragma unroll
    for (int j = 0; j < 4; j++) acc[i][j] = (floatx4){0.f, 0.f, 0.f, 0.f};

  for (int k0 = 0; k0 < K; k0 += 64) {
#pragma unroll
    for (int kh = 0; kh < 2; kh++)
#pragma unroll
      for (int j = 0; j < 2; j++) {
        gload_lds16(A + (size_t)(m0 + arow + j * 16) * K + k0 + kh * 32 + acol,
                    &Al[kh][(w * 32 + j * 16) * 32]);
        gload_lds16(Bt + (size_t)(n0 + arow + j * 16) * K + k0 + kh * 32 + acol,
                    &Bl[kh][(w * 32 + j * 16) * 32]);
      }
    __syncthreads();
#pragma unroll
    for (int kh = 0; kh < 2; kh++) {
      bf16x8 af[4], bfr[4];
#pragma unroll
      for (int mt = 0; mt < 4; mt++)
        af[mt] =
            *(const bf16x8*)&Al[kh][(mw * 64 + mt * 16 + l16) * 32 + quad * 8];
#pragma unroll
      for (int nt = 0; nt < 4; nt++)
        bfr[nt] =
            *(const bf16x8*)&Bl[kh][(nw * 64 + nt * 16 + l16) * 32 + quad * 8];
#pragma unroll
      for (int mt = 0; mt < 4; mt++)
#pragma unroll
        for (int nt = 0; nt < 4; nt++)
          acc[mt][nt] = MFMA(af[mt], bfr[nt], acc[mt][nt]);
    }
    __syncthreads();
  }
#pragma unroll
  for (int mt = 0; mt < 4; mt++)
#pragma unroll
    for (int nt = 0; nt < 4; nt++)
#pragma unroll
      for (int r = 0; r < 4; r++) {
        int row = m0 + mw * 64 + mt * 16 + quad * 4 + r;
        int col = n0 + nw * 64 + nt * 16 + l16;
        C[(size_t)row * N + col] = (__bf16)(acc[mt][nt][r] * sc);
      }
}

// ---------- gemm_kv128: k = ckv@Wuk' (bx<8); vt = (ckv@Wuv')^T (bx>=8) ------
__global__ __launch_bounds__(256) void gemm_kv128(const __bf16* __restrict__ A,
                                                  const __bf16* __restrict__ Bk,
                                                  const __bf16* __restrict__ Bv,
                                                  __bf16* __restrict__ k,
                                                  __bf16* __restrict__ vt) {
  __shared__ __attribute__((aligned(16))) __bf16 Al[2][BUFE];
  __shared__ __attribute__((aligned(16))) __bf16 Bl[2][BUFE];
  __shared__ __attribute__((aligned(16))) __bf16 tw[4][64 * 72];
  int tid = threadIdx.x;
  int w = tid >> 6, lane = tid & 63;
  int quad = lane >> 4, l16 = lane & 15;
  int mw = w & 1, nw = w >> 1;
  int bx = blockIdx.x, m0 = blockIdx.y * 128;
  bool is_k = (bx < 8);
  const __bf16* Bt = is_k ? Bk : Bv;
  int n0 = (is_k ? bx : bx - 8) * 128;
  const int K = DLAT;
  int arow = w * 32 + (lane >> 2), acol = (lane & 3) << 3;

  floatx4 acc[4][4];
#pragma unroll
  for (int i = 0; i < 4; i++)
#pragma unroll
    for (int j = 0; j < 4; j++) acc[i][j] = (floatx4){0.f, 0.f, 0.f, 0.f};

  for (int k0 = 0; k0 < K; k0 += 64) {
#pragma unroll
    for (int kh = 0; kh < 2; kh++)
#pragma unroll
      for (int j = 0; j < 2; j++) {
        gload_lds16(A + (size_t)(m0 + arow + j * 16) * K + k0 + kh * 32 + acol,
                    &Al[kh][(w * 32 + j * 16) * 32]);
        gload_lds16(Bt + (size_t)(n0 + arow + j * 16) * K + k0 + kh * 32 + acol,
                    &Bl[kh][(w * 32 + j * 16) * 32]);
      }
    __syncthreads();
#pragma unroll
    for (int kh = 0; kh < 2; kh++) {
      bf16x8 af[4], bfr[4];
#pragma unroll
      for (int mt = 0; mt < 4; mt++)
        af[mt] =
            *(const bf16x8*)&Al[kh][(mw * 64 + mt * 16 + l16) * 32 + quad * 8];
#pragma unroll
      for (int nt = 0; nt < 4; nt++)
        bfr[nt] =
            *(const bf16x8*)&Bl[kh][(nw * 64 + nt * 16 + l16) * 32 + quad * 8];
#pragma unroll
      for (int mt = 0; mt < 4; mt++)
#pragma unroll
        for (int nt = 0; nt < 4; nt++)
          acc[mt][nt] = MFMA(af[mt], bfr[nt], acc[mt][nt]);
    }
    __syncthreads();
  }
  if (is_k) {
#pragma unroll
    for (int mt = 0; mt < 4; mt++)
#pragma unroll
      for (int nt = 0; nt < 4; nt++)
#pragma unroll
        for (int r = 0; r < 4; r++) {
          int row = m0 + mw * 64 + mt * 16 + quad * 4 + r;
          int col = n0 + nw * 64 + nt * 16 + l16;
          k[(size_t)row * DIMX + col] = (__bf16)acc[mt][nt][r];
        }
  } else {
#pragma unroll
    for (int mt = 0; mt < 4; mt++)
#pragma unroll
      for (int nt = 0; nt < 4; nt++)
#pragma unroll
        for (int r = 0; r < 4; r++)
          tw[w][(nt * 16 + l16) * 72 + mt * 16 + quad * 4 + r] =
              (__bf16)acc[mt][nt][r];
    int cbase = lane >> 3, chunk = lane & 7;
#pragma unroll
    for (int i = 0; i < 8; i++) {
      int c = cbase + i * 8;
      bf16x8 v8 = *(const bf16x8*)&tw[w][c * 72 + chunk * 8];
      *(bf16x8*)&vt[(size_t)(n0 + nw * 64 + c) * T_SEQ + m0 + mw * 64 +
                    chunk * 8] = v8;
    }
  }
}

// ---------- gemm_f128: out(f32) = ctx @ Wo' -------------------------------
__global__ __launch_bounds__(256) void gemm_f128(const __bf16* __restrict__ A,
                                                 const __bf16* __restrict__ Bt,
                                                 float* __restrict__ C) {
  __shared__ __attribute__((aligned(16))) __bf16 Al[2][BUFE];
  __shared__ __attribute__((aligned(16))) __bf16 Bl[2][BUFE];
  int tid = threadIdx.x;
  int w = tid >> 6, lane = tid & 63;
  int quad = lane >> 4, l16 = lane & 15;
  int mw = w & 1, nw = w >> 1;
  int n0 = blockIdx.x * 128, m0 = blockIdx.y * 128;
  const int K = DIMX, N = DIMX;
  int arow = w * 32 + (lane >> 2), acol = (lane & 3) << 3;

  floatx4 acc[4][4];
#pragma unroll
  for (int i = 0; i < 4; i++)
#pragma unroll
    for (int j = 0; j < 4; j++) acc[i][j] = (floatx4){0.f, 0.f, 0.f, 0.f};

  for (int k0 = 0; k0 < K; k0 += 64) {
#pragma unroll
    for (int kh = 0; kh < 2; kh++)
#pragma unroll
      for (int j = 0; j < 2; j++) {
        gload_lds16(A + (size_t)(m0 + arow + j * 16) * K + k0 + kh * 32 + acol,
                    &Al[kh][(w * 32 + j * 16) * 32]);
        gload_lds16(Bt + (size_t)(n0 + arow + j * 16) * K + k0 + kh * 32 + acol,
                    &Bl[kh][(w * 32 + j * 16) * 32]);
      }
    __syncthreads();
#pragma unroll
    for (int kh = 0; kh < 2; kh++) {
      bf16x8 af[4], bfr[4];
#pragma unroll
      for (int mt = 0; mt < 4; mt++)
        af[mt] =
            *(const bf16x8*)&Al[kh][(mw * 64 + mt * 16 + l16) * 32 + quad * 8];
#pragma unroll
      for (int nt = 0; nt < 4; nt++)
        bfr[nt] =
            *(const bf16x8*)&Bl[kh][(nw * 64 + nt * 16 + l16) * 32 + quad * 8];
#pragma unroll
      for (int mt = 0; mt < 4; mt++)
#pragma unroll
        for (int nt = 0; nt < 4; nt++)
          acc[mt][nt] = MFMA(af[mt], bfr[nt], acc[mt][nt]);
    }
    __syncthreads();
  }
#pragma unroll
  for (int mt = 0; mt < 4; mt++)
#pragma unroll
    for (int nt = 0; nt < 4; nt++)
#pragma unroll
      for (int r = 0; r < 4; r++) {
        int row = m0 + mw * 64 + mt * 16 + quad * 4 + r;
        int col = n0 + nw * 64 + nt * 16 + l16;
        C[(size_t)row * N + col] = acc[mt][nt][r];
      }
}

// ---------- flash attention v9: V in registers + global-LPT grid ------------
// r4 lesson: per-head LPT made the big late-head blocks start last (tail).
// Fix: dim3(NH, 64), heads fastest, qt = 63 - blockIdx.y -> all cost-64 blocks
// dispatch first, cost-1 backfill. V leaves LDS: double-buffered in registers
// (vc cur / vn next), cutting LDS cycles/unit ~42% and removing V from the
// barrier-to-barrier chain. LDS = 25.6 KB -> 3 blocks/CU resident.
#define PST 72
__global__ __launch_bounds__(256, 3) void mla_attn9(const __bf16* __restrict__ Q,
                                                    const __bf16* __restrict__ Kg,
                                                    const __bf16* __restrict__ Vt,
                                                    __bf16* __restrict__ ctx) {
  __shared__ __attribute__((aligned(16))) __bf16 Kl[2][64 * 64];
  __shared__ __attribute__((aligned(16))) __bf16 Pl[64 * PST];
  int tid = threadIdx.x;
  int wave = tid >> 6, lane = tid & 63;
  int quad = lane >> 4, l16 = lane & 15;
  int h = blockIdx.x;        // heads vary fastest in dispatch order
  int qt = 63 - blockIdx.y;  // global LPT: all large blocks dispatch first
  int q0 = qt * 64;
  int srow = tid >> 3, pos = tid & 7;  // srow 0..31, rows srow and srow+32
  int gco = pos << 3;
  int sw = (pos ^ (srow & 7)) << 3;
  int swr = srow * 64 + sw;
  int fr = (wave * 16 + l16) * PST;
  int c0s = ((quad ^ (l16 & 7)) << 3);
  int c1s = (((4 + quad) ^ (l16 & 7)) << 3);
  // per-lane V pointer: row h*HD + l16 (+dt*16), col quad*8 (+kt*64 +hf*32)
  const __bf16* vptr = Vt + (size_t)(h * HD + l16) * T_SEQ + quad * 8;

  // stage Q (2 rows/thread) + K tile 0; V tile 0 straight to registers
  *(bf16x8*)&Pl[srow * PST + gco] =
      *(const bf16x8*)&Q[(size_t)(q0 + srow) * DIMX + h * HD + gco];
  *(bf16x8*)&Pl[(srow + 32) * PST + gco] =
      *(const bf16x8*)&Q[(size_t)(q0 + srow + 32) * DIMX + h * HD + gco];
  *(bf16x8*)&Kl[0][swr] =
      *(const bf16x8*)&Kg[(size_t)srow * DIMX + h * HD + gco];
  *(bf16x8*)&Kl[0][swr + 2048] =
      *(const bf16x8*)&Kg[(size_t)(srow + 32) * DIMX + h * HD + gco];
  bf16x8 vc[8], vn[8];
#pragma unroll
  for (int dt = 0; dt < 4; dt++)
#pragma unroll
    for (int hf = 0; hf < 2; hf++)
      vc[dt * 2 + hf] =
          *(const bf16x8*)&vptr[(size_t)(dt * 16) * T_SEQ + hf * 32];
  __syncthreads();
  bf16x8 qf0 = *(const bf16x8*)&Pl[fr + quad * 8];
  bf16x8 qf1 = *(const bf16x8*)&Pl[fr + 32 + quad * 8];

  floatx4 o[4];
  float lsum = 0.f;
#pragma unroll
  for (int i = 0; i < 4; i++) o[i] = (floatx4){0.f, 0.f, 0.f, 0.f};

  for (int kt = 0; kt <= qt; kt++) {
    int cur = kt & 1, nxt = cur ^ 1;
    bool pre = (kt < qt);
    bf16x8 kp0, kp1;
    if (pre) {
      int k0n = (kt + 1) * 64;
      kp0 = *(const bf16x8*)&Kg[(size_t)(k0n + srow) * DIMX + h * HD + gco];
      kp1 = *(const bf16x8*)&Kg[(size_t)(k0n + srow + 32) * DIMX + h * HD + gco];
#pragma unroll
      for (int dt = 0; dt < 4; dt++)
#pragma unroll
        for (int hf = 0; hf < 2; hf++)
          vn[dt * 2 + hf] = *(const bf16x8*)&vptr[(size_t)(dt * 16) * T_SEQ +
                                                  k0n + hf * 32];
    }
    const __bf16* Kc = Kl[cur];
    floatx4 s[4];
    __builtin_amdgcn_s_setprio(1);
#pragma unroll
    for (int ct = 0; ct < 4; ct++) {
      int rb = (ct * 16 + l16) * 64;
      bf16x8 kf0 = *(const bf16x8*)&Kc[rb + c0s];
      bf16x8 kf1 = *(const bf16x8*)&Kc[rb + c1s];
      floatx4 z = (floatx4){0.f, 0.f, 0.f, 0.f};
      z = MFMA(kf0, qf0, z);  // swapped: lane holds P[q=l16][k=ct*16+quad*4+r]
      z = MFMA(kf1, qf1, z);
      s[ct] = z;
    }
    __builtin_amdgcn_s_setprio(0);
    bool diag = (kt == qt);
#pragma unroll
    for (int ct = 0; ct < 4; ct++) {
      float p0[4];
#pragma unroll
      for (int r = 0; r < 4; r++) {
        float p = __builtin_amdgcn_exp2f(s[ct][r]);
        if (diag && (ct * 16 + quad * 4 + r > wave * 16 + l16)) p = 0.f;
        lsum += p;
        p0[r] = p;
      }
      bf16x4 pk = {(__bf16)p0[0], (__bf16)p0[1], (__bf16)p0[2], (__bf16)p0[3]};
      *(bf16x4*)&Pl[(wave * 16 + l16) * PST + ct * 16 + quad * 4] = pk;
    }
    bf16x8 pf0 = *(const bf16x8*)&Pl[fr + quad * 8];
    bf16x8 pf1 = *(const bf16x8*)&Pl[fr + 32 + quad * 8];
    __builtin_amdgcn_s_setprio(1);
#pragma unroll
    for (int dt = 0; dt < 4; dt++) {
      o[dt] = MFMA(pf0, vc[dt * 2 + 0], o[dt]);
      o[dt] = MFMA(pf1, vc[dt * 2 + 1], o[dt]);
    }
    __builtin_amdgcn_s_setprio(0);
    if (pre) {
      *(bf16x8*)&Kl[nxt][swr] = kp0;
      *(bf16x8*)&Kl[nxt][swr + 2048] = kp1;
#pragma unroll
      for (int i = 0; i < 8; i++) vc[i] = vn[i];
    }
    __syncthreads();
  }

  // row sums: lane holds partial for q=l16 over its k-subset; reduce quads.
  lsum += __shfl_xor(lsum, 16, 64);
  lsum += __shfl_xor(lsum, 32, 64);
  float inv[4];
#pragma unroll
  for (int r = 0; r < 4; r++) inv[r] = 1.0f / __shfl(lsum, quad * 4 + r, 16);

#pragma unroll
  for (int dt = 0; dt < 4; dt++)
#pragma unroll
    for (int r = 0; r < 4; r++) {
      float val = o[dt][r] * inv[r];
      int row = q0 + wave * 16 + quad * 4 + r;
      int col = h * HD + dt * 16 + l16;
      ctx[(size_t)row * DIMX + col] = (__bf16)val;
    }
}

extern "C" void kernel_launch(void* const* d_in, const int* in_sizes, int n_in,
                              void* d_out, int out_size, void* d_ws,
                              size_t ws_size, hipStream_t stream) {
  const float* x = (const float*)d_in[0];
  const float* wdkv = (const float*)d_in[1];
  const float* wuk = (const float*)d_in[2];
  const float* wuv = (const float*)d_in[3];
  const float* wuq = (const float*)d_in[4];
  const float* wo = (const float*)d_in[5];
  float* out = (float*)d_out;

  __bf16* ws = (__bf16*)d_ws;
  __bf16* x_bf = ws;                               // T*D
  __bf16* q = x_bf + (size_t)T_SEQ * DIMX;         // T*D (pre-scaled)
  __bf16* k = q + (size_t)T_SEQ * DIMX;            // T*D
  __bf16* vt = k + (size_t)T_SEQ * DIMX;           // D*T
  __bf16* ctx = vt + (size_t)T_SEQ * DIMX;         // T*D
  __bf16* ckv = ctx + (size_t)T_SEQ * DIMX;        // T*DLAT
  __bf16* wt_dkv = ckv + (size_t)T_SEQ * DLAT;     // DLAT x DIM
  __bf16* wt_uk = wt_dkv + (size_t)DLAT * DIMX;    // DIM x DLAT
  __bf16* wt_uv = wt_uk + (size_t)DIMX * DLAT;     // DIM x DLAT
  __bf16* wt_uq = wt_uv + (size_t)DIMX * DLAT;     // DIM x DIM
  __bf16* wt_o = wt_uq + (size_t)DIMX * DIMX;      // DIM x DIM

  dim3 blk(256);
  prep_kernel<<<dim3(2752), blk, 0, stream>>>(x, wdkv, wuk, wuv, wuq, wo, x_bf,
                                              wt_dkv, wt_uk, wt_uv, wt_uq, wt_o);
  gemm_a128<<<dim3(10, T_SEQ / 128), blk, 0, stream>>>(x_bf, wt_dkv, wt_uq,
                                                       ckv, q);
  gemm_kv128<<<dim3(16, T_SEQ / 128), blk, 0, stream>>>(ckv, wt_uk, wt_uv, k,
                                                        vt);
  mla_attn9<<<dim3(NH, 64), dim3(256), 0, stream>>>(q, k, vt, ctx);
  gemm_f128<<<dim3(DIMX / 128, T_SEQ / 128), blk, 0, stream>>>(ctx, wt_o, out);
}

// Round 7
// 238.456 us; speedup vs baseline: 1.1760x; 1.1760x over previous
//
#include <hip/hip_runtime.h>
#include <hip/hip_bf16.h>
#include <stdint.h>

#define T_SEQ 4096
#define DIMX 1024
#define NH 16
#define HD 64
#define DLAT 256

typedef __bf16 bf16x8 __attribute__((ext_vector_type(8)));
typedef __bf16 bf16x4 __attribute__((ext_vector_type(4)));
typedef float floatx4 __attribute__((ext_vector_type(4)));
typedef short short4v __attribute__((ext_vector_type(4)));

#define MFMA(a, b, c) __builtin_amdgcn_mfma_f32_16x16x32_bf16(a, b, c, 0, 0, 0)

// 16x16x16 bf16 MFMA (K=16, 2-VGPR operands). Builtin name differs across
// ROCm versions; hedge with has_builtin, fall back to inline asm.
#if defined(__has_builtin)
#if __has_builtin(__builtin_amdgcn_mfma_f32_16x16x16bf16_1k)
#define MFMA16(a, b, c)                                                     \
  __builtin_amdgcn_mfma_f32_16x16x16bf16_1k(__builtin_bit_cast(short4v, a), \
                                            __builtin_bit_cast(short4v, b), \
                                            c, 0, 0, 0)
#elif __has_builtin(__builtin_amdgcn_mfma_f32_16x16x16_bf16)
#define MFMA16(a, b, c) __builtin_amdgcn_mfma_f32_16x16x16_bf16(a, b, c, 0, 0, 0)
#endif
#endif
#ifndef MFMA16
static inline __device__ floatx4 mfma16_asm(bf16x4 a, bf16x4 b, floatx4 c) {
  asm volatile("v_mfma_f32_16x16x16_bf16 %0, %1, %2, %0"
               : "+v"(c)
               : "v"(a), "v"(b));
  return c;
}
#define MFMA16(a, b, c) mfma16_asm(a, b, c)
#endif

__device__ inline void gload_lds16(const __bf16* g, __bf16* l) {
  __builtin_amdgcn_global_load_lds(
      (const __attribute__((address_space(1))) uint32_t*)g,
      (__attribute__((address_space(3))) uint32_t*)l, 16, 0, 0);
}

// ---------- prep: x f32->bf16 convert + 5 weight transposes (round-8) -------
__global__ __launch_bounds__(256) void prep_kernel(
    const float* __restrict__ x, const float* __restrict__ wdkv,
    const float* __restrict__ wuk, const float* __restrict__ wuv,
    const float* __restrict__ wuq, const float* __restrict__ wo,
    __bf16* __restrict__ x_bf, __bf16* __restrict__ wt_dkv,
    __bf16* __restrict__ wt_uk, __bf16* __restrict__ wt_uv,
    __bf16* __restrict__ wt_uq, __bf16* __restrict__ wt_o) {
  int id = blockIdx.x;
  if (id < 2048) {
    int i = id * 256 + threadIdx.x;
    const float4* p = (const float4*)x;
    float4 a = p[2 * i], b = p[2 * i + 1];
    bf16x8 r = {(__bf16)a.x, (__bf16)a.y, (__bf16)a.z, (__bf16)a.w,
                (__bf16)b.x, (__bf16)b.y, (__bf16)b.z, (__bf16)b.w};
    *(bf16x8*)(x_bf + 8 * (size_t)i) = r;
    return;
  }
  int t = id - 2048;
  const float* in;
  __bf16* out;
  int R, C, lt;
  if (t < 64)       { in = wdkv; out = wt_dkv; R = 1024; C = 256;  lt = t; }
  else if (t < 128) { in = wuk;  out = wt_uk;  R = 256;  C = 1024; lt = t - 64; }
  else if (t < 192) { in = wuv;  out = wt_uv;  R = 256;  C = 1024; lt = t - 128; }
  else if (t < 448) { in = wuq;  out = wt_uq;  R = 1024; C = 1024; lt = t - 192; }
  else              { in = wo;   out = wt_o;   R = 1024; C = 1024; lt = t - 448; }
  __shared__ __bf16 tls[64][65];
  int tpr = C >> 6;
  int r0 = (lt / tpr) * 64, c0 = (lt % tpr) * 64;
  int tid = threadIdx.x;
#pragma unroll
  for (int i = 0; i < 16; i++) {
    int idx = tid + i * 256;
    int r = idx >> 6, c = idx & 63;
    tls[r][c] = (__bf16)in[(size_t)(r0 + r) * C + c0 + c];
  }
  __syncthreads();
#pragma unroll
  for (int i = 0; i < 16; i++) {
    int idx = tid + i * 256;
    int rr = idx & 63, cc = idx >> 6;
    out[(size_t)(c0 + cc) * R + r0 + rr] = tls[rr][cc];
  }
}

// ======== 128x128 GEMM, BK=64 via two independent BK=32 buffers =============
#define BUFE 4096  // 128*32

// ---------- gemm_a128: ckv = x@Wdkv' (bx<2), q = s*x@Wuq' (bx>=2) -----------
// q scale folds 1/8 (softmax scale) * log2(e) so attn can use exp2.
__global__ __launch_bounds__(256) void gemm_a128(const __bf16* __restrict__ A,
                                                 const __bf16* __restrict__ B1,
                                                 const __bf16* __restrict__ B2,
                                                 __bf16* __restrict__ C1,
                                                 __bf16* __restrict__ C2) {
  __shared__ __attribute__((aligned(16))) __bf16 Al[2][BUFE];
  __shared__ __attribute__((aligned(16))) __bf16 Bl[2][BUFE];
  int tid = threadIdx.x;
  int w = tid >> 6, lane = tid & 63;
  int quad = lane >> 4, l16 = lane & 15;
  int mw = w & 1, nw = w >> 1;
  int bx = blockIdx.x, m0 = blockIdx.y * 128;
  const __bf16* Bt;
  __bf16* C;
  int n0, N;
  float sc;
  if (bx < 2) { Bt = B1; C = C1; n0 = bx * 128; N = DLAT; sc = 1.0f; }
  else        { Bt = B2; C = C2; n0 = (bx - 2) * 128; N = DIMX;
                sc = 0.125f * 1.44269504088896340736f; }
  const int K = DIMX;
  int arow = w * 32 + (lane >> 2), acol = (lane & 3) << 3;

  floatx4 acc[4][4];
#pragma unroll
  for (int i = 0; i < 4; i++)
#pragma unroll
    for (int j = 0; j < 4; j++) acc[i][j] = (floatx4){0.f, 0.f, 0.f, 0.f};

  for (int k0 = 0; k0 < K; k0 += 64) {
#pragma unroll
    for (int kh = 0; kh < 2; kh++)
#pragma unroll
      for (int j = 0; j < 2; j++) {
        gload_lds16(A + (size_t)(m0 + arow + j * 16) * K + k0 + kh * 32 + acol,
                    &Al[kh][(w * 32 + j * 16) * 32]);
        gload_lds16(Bt + (size_t)(n0 + arow + j * 16) * K + k0 + kh * 32 + acol,
                    &Bl[kh][(w * 32 + j * 16) * 32]);
      }
    __syncthreads();
#pragma unroll
    for (int kh = 0; kh < 2; kh++) {
      bf16x8 af[4], bfr[4];
#pragma unroll
      for (int mt = 0; mt < 4; mt++)
        af[mt] =
            *(const bf16x8*)&Al[kh][(mw * 64 + mt * 16 + l16) * 32 + quad * 8];
#pragma unroll
      for (int nt = 0; nt < 4; nt++)
        bfr[nt] =
            *(const bf16x8*)&Bl[kh][(nw * 64 + nt * 16 + l16) * 32 + quad * 8];
#pragma unroll
      for (int mt = 0; mt < 4; mt++)
#pragma unroll
        for (int nt = 0; nt < 4; nt++)
          acc[mt][nt] = MFMA(af[mt], bfr[nt], acc[mt][nt]);
    }
    __syncthreads();
  }
#pragma unroll
  for (int mt = 0; mt < 4; mt++)
#pragma unroll
    for (int nt = 0; nt < 4; nt++)
#pragma unroll
      for (int r = 0; r < 4; r++) {
        int row = m0 + mw * 64 + mt * 16 + quad * 4 + r;
        int col = n0 + nw * 64 + nt * 16 + l16;
        C[(size_t)row * N + col] = (__bf16)(acc[mt][nt][r] * sc);
      }
}

// ---------- gemm_kv128: k = ckv@Wuk' (bx<8); vt = (ckv@Wuv')^T (bx>=8) ------
__global__ __launch_bounds__(256) void gemm_kv128(const __bf16* __restrict__ A,
                                                  const __bf16* __restrict__ Bk,
                                                  const __bf16* __restrict__ Bv,
                                                  __bf16* __restrict__ k,
                                                  __bf16* __restrict__ vt) {
  __shared__ __attribute__((aligned(16))) __bf16 Al[2][BUFE];
  __shared__ __attribute__((aligned(16))) __bf16 Bl[2][BUFE];
  __shared__ __attribute__((aligned(16))) __bf16 tw[4][64 * 72];
  int tid = threadIdx.x;
  int w = tid >> 6, lane = tid & 63;
  int quad = lane >> 4, l16 = lane & 15;
  int mw = w & 1, nw = w >> 1;
  int bx = blockIdx.x, m0 = blockIdx.y * 128;
  bool is_k = (bx < 8);
  const __bf16* Bt = is_k ? Bk : Bv;
  int n0 = (is_k ? bx : bx - 8) * 128;
  const int K = DLAT;
  int arow = w * 32 + (lane >> 2), acol = (lane & 3) << 3;

  floatx4 acc[4][4];
#pragma unroll
  for (int i = 0; i < 4; i++)
#pragma unroll
    for (int j = 0; j < 4; j++) acc[i][j] = (floatx4){0.f, 0.f, 0.f, 0.f};

  for (int k0 = 0; k0 < K; k0 += 64) {
#pragma unroll
    for (int kh = 0; kh < 2; kh++)
#pragma unroll
      for (int j = 0; j < 2; j++) {
        gload_lds16(A + (size_t)(m0 + arow + j * 16) * K + k0 + kh * 32 + acol,
                    &Al[kh][(w * 32 + j * 16) * 32]);
        gload_lds16(Bt + (size_t)(n0 + arow + j * 16) * K + k0 + kh * 32 + acol,
                    &Bl[kh][(w * 32 + j * 16) * 32]);
      }
    __syncthreads();
#pragma unroll
    for (int kh = 0; kh < 2; kh++) {
      bf16x8 af[4], bfr[4];
#pragma unroll
      for (int mt = 0; mt < 4; mt++)
        af[mt] =
            *(const bf16x8*)&Al[kh][(mw * 64 + mt * 16 + l16) * 32 + quad * 8];
#pragma unroll
      for (int nt = 0; nt < 4; nt++)
        bfr[nt] =
            *(const bf16x8*)&Bl[kh][(nw * 64 + nt * 16 + l16) * 32 + quad * 8];
#pragma unroll
      for (int mt = 0; mt < 4; mt++)
#pragma unroll
        for (int nt = 0; nt < 4; nt++)
          acc[mt][nt] = MFMA(af[mt], bfr[nt], acc[mt][nt]);
    }
    __syncthreads();
  }
  if (is_k) {
#pragma unroll
    for (int mt = 0; mt < 4; mt++)
#pragma unroll
      for (int nt = 0; nt < 4; nt++)
#pragma unroll
        for (int r = 0; r < 4; r++) {
          int row = m0 + mw * 64 + mt * 16 + quad * 4 + r;
          int col = n0 + nw * 64 + nt * 16 + l16;
          k[(size_t)row * DIMX + col] = (__bf16)acc[mt][nt][r];
        }
  } else {
#pragma unroll
    for (int mt = 0; mt < 4; mt++)
#pragma unroll
      for (int nt = 0; nt < 4; nt++)
#pragma unroll
        for (int r = 0; r < 4; r++)
          tw[w][(nt * 16 + l16) * 72 + mt * 16 + quad * 4 + r] =
              (__bf16)acc[mt][nt][r];
    int cbase = lane >> 3, chunk = lane & 7;
#pragma unroll
    for (int i = 0; i < 8; i++) {
      int c = cbase + i * 8;
      bf16x8 v8 = *(const bf16x8*)&tw[w][c * 72 + chunk * 8];
      *(bf16x8*)&vt[(size_t)(n0 + nw * 64 + c) * T_SEQ + m0 + mw * 64 +
                    chunk * 8] = v8;
    }
  }
}

// ---------- gemm_f128: out(f32) = ctx @ Wo' -------------------------------
__global__ __launch_bounds__(256) void gemm_f128(const __bf16* __restrict__ A,
                                                 const __bf16* __restrict__ Bt,
                                                 float* __restrict__ C) {
  __shared__ __attribute__((aligned(16))) __bf16 Al[2][BUFE];
  __shared__ __attribute__((aligned(16))) __bf16 Bl[2][BUFE];
  int tid = threadIdx.x;
  int w = tid >> 6, lane = tid & 63;
  int quad = lane >> 4, l16 = lane & 15;
  int mw = w & 1, nw = w >> 1;
  int n0 = blockIdx.x * 128, m0 = blockIdx.y * 128;
  const int K = DIMX, N = DIMX;
  int arow = w * 32 + (lane >> 2), acol = (lane & 3) << 3;

  floatx4 acc[4][4];
#pragma unroll
  for (int i = 0; i < 4; i++)
#pragma unroll
    for (int j = 0; j < 4; j++) acc[i][j] = (floatx4){0.f, 0.f, 0.f, 0.f};

  for (int k0 = 0; k0 < K; k0 += 64) {
#pragma unroll
    for (int kh = 0; kh < 2; kh++)
#pragma unroll
      for (int j = 0; j < 2; j++) {
        gload_lds16(A + (size_t)(m0 + arow + j * 16) * K + k0 + kh * 32 + acol,
                    &Al[kh][(w * 32 + j * 16) * 32]);
        gload_lds16(Bt + (size_t)(n0 + arow + j * 16) * K + k0 + kh * 32 + acol,
                    &Bl[kh][(w * 32 + j * 16) * 32]);
      }
    __syncthreads();
#pragma unroll
    for (int kh = 0; kh < 2; kh++) {
      bf16x8 af[4], bfr[4];
#pragma unroll
      for (int mt = 0; mt < 4; mt++)
        af[mt] =
            *(const bf16x8*)&Al[kh][(mw * 64 + mt * 16 + l16) * 32 + quad * 8];
#pragma unroll
      for (int nt = 0; nt < 4; nt++)
        bfr[nt] =
            *(const bf16x8*)&Bl[kh][(nw * 64 + nt * 16 + l16) * 32 + quad * 8];
#pragma unroll
      for (int mt = 0; mt < 4; mt++)
#pragma unroll
        for (int nt = 0; nt < 4; nt++)
          acc[mt][nt] = MFMA(af[mt], bfr[nt], acc[mt][nt]);
    }
    __syncthreads();
  }
#pragma unroll
  for (int mt = 0; mt < 4; mt++)
#pragma unroll
    for (int nt = 0; nt < 4; nt++)
#pragma unroll
      for (int r = 0; r < 4; r++) {
        int row = m0 + mw * 64 + mt * 16 + quad * 4 + r;
        int col = n0 + nw * 64 + nt * 16 + l16;
        C[(size_t)row * N + col] = acc[mt][nt][r];
      }
}

// ---------- flash attention v10: k-split waves, barrier-free main loop ------
// Wave w owns k-rows w*16..w*16+15 of each 64-k tile; operands are
// wave-exclusive so K and V go global->reg directly (no LDS, no barriers,
// no redundancy). Swapped QK output (lane: q=l16, k=quad*4+r) is exactly the
// 16x16x16 A-fragment layout, so P feeds PV from registers (no LDS P).
// Waves meet once at the end: O/lsum pair-reduced via LDS, 2 barriers.
__global__ __launch_bounds__(256, 2) void mla_attn10(
    const __bf16* __restrict__ Q, const __bf16* __restrict__ Kg,
    const __bf16* __restrict__ Vt, __bf16* __restrict__ ctx) {
  __shared__ float OlA[64][68];
  __shared__ float OlB[64][68];
  __shared__ float lslA[64], lslB[64];
  int tid = threadIdx.x;
  int wave = tid >> 6, lane = tid & 63;
  int quad = lane >> 4, l16 = lane & 15;
  int h = blockIdx.x;        // heads fastest in dispatch order
  int qt = 63 - blockIdx.y;  // global LPT: large blocks first
  int q0 = qt * 64;

  // loop-invariant Q fragments (B-operand): q = q0+ct*16+l16, d = hf*32+quad*8
  bf16x8 qf[4][2];
#pragma unroll
  for (int ct = 0; ct < 4; ct++)
#pragma unroll
    for (int hf = 0; hf < 2; hf++)
      qf[ct][hf] = *(const bf16x8*)&Q[(size_t)(q0 + ct * 16 + l16) * DIMX +
                                      h * HD + hf * 32 + quad * 8];

  const __bf16* kb = Kg + h * HD;
  // K cur (A-operand): token row = wave*16+l16, d = hf*32+quad*8 (kt = 0)
  bf16x8 kc0 = *(const bf16x8*)&kb[(size_t)(wave * 16 + l16) * DIMX + quad * 8];
  bf16x8 kc1 =
      *(const bf16x8*)&kb[(size_t)(wave * 16 + l16) * DIMX + 32 + quad * 8];
  // V cur (16x16x16 B-operand): d row = dt*16+l16, token = wave*16+quad*4+e
  bf16x4 vc[4];
#pragma unroll
  for (int dt = 0; dt < 4; dt++)
    vc[dt] = *(const bf16x4*)&Vt[(size_t)(h * HD + dt * 16 + l16) * T_SEQ +
                                 wave * 16 + quad * 4];

  floatx4 o[4][4];
  float ls[4];
#pragma unroll
  for (int ct = 0; ct < 4; ct++) {
    ls[ct] = 0.f;
#pragma unroll
    for (int dt = 0; dt < 4; dt++) o[ct][dt] = (floatx4){0.f, 0.f, 0.f, 0.f};
  }

  for (int kt = 0; kt <= qt; kt++) {
    bool pre = (kt < qt);
    bf16x8 kn0, kn1;
    bf16x4 vn[4];
    if (pre) {  // prefetch next tile's wave-slice (wave-exclusive, 1x traffic)
      int t1 = (kt + 1) * 64 + wave * 16;
      kn0 = *(const bf16x8*)&kb[(size_t)(t1 + l16) * DIMX + quad * 8];
      kn1 = *(const bf16x8*)&kb[(size_t)(t1 + l16) * DIMX + 32 + quad * 8];
#pragma unroll
      for (int dt = 0; dt < 4; dt++)
        vn[dt] = *(const bf16x4*)&Vt[(size_t)(h * HD + dt * 16 + l16) * T_SEQ +
                                     t1 + quad * 4];
    }
    floatx4 s[4];
    __builtin_amdgcn_s_setprio(1);
#pragma unroll
    for (int ct = 0; ct < 4; ct++) {
      floatx4 z = (floatx4){0.f, 0.f, 0.f, 0.f};
      z = MFMA(kc0, qf[ct][0], z);  // lane: q=l16 (B-col), token=quad*4+r
      z = MFMA(kc1, qf[ct][1], z);
      s[ct] = z;
    }
    __builtin_amdgcn_s_setprio(0);
    bool diag = (kt == qt);
    bf16x4 pf[4];
#pragma unroll
    for (int ct = 0; ct < 4; ct++) {
      float p0[4];
#pragma unroll
      for (int r = 0; r < 4; r++) {
        float p = __builtin_amdgcn_exp2f(s[ct][r]);
        if (diag && (wave * 16 + quad * 4 + r > ct * 16 + l16)) p = 0.f;
        ls[ct] += p;
        p0[r] = p;
      }
      // exactly the 16x16x16 A-frag: row=l16=q, k=quad*4+e — no shuffle.
      pf[ct] = (bf16x4){(__bf16)p0[0], (__bf16)p0[1], (__bf16)p0[2],
                        (__bf16)p0[3]};
    }
    __builtin_amdgcn_s_setprio(1);
#pragma unroll
    for (int ct = 0; ct < 4; ct++)
#pragma unroll
      for (int dt = 0; dt < 4; dt++)
        o[ct][dt] = MFMA16(pf[ct], vc[dt], o[ct][dt]);
    __builtin_amdgcn_s_setprio(0);
    if (pre) {
      kc0 = kn0;
      kc1 = kn1;
#pragma unroll
      for (int dt = 0; dt < 4; dt++) vc[dt] = vn[dt];
    }
  }

  // reduce lsum across quads (within wave's k-slice)
#pragma unroll
  for (int ct = 0; ct < 4; ct++) {
    ls[ct] += __shfl_xor(ls[ct], 16, 64);
    ls[ct] += __shfl_xor(ls[ct], 32, 64);
  }

  // cross-wave reduce: pairs (0,2)->A, (1,3)->B in parallel, merge at store.
  float(*Ol)[68] = (wave & 1) ? OlB : OlA;
  float* lsl = (wave & 1) ? lslB : lslA;
  if (wave < 2) {
#pragma unroll
    for (int ct = 0; ct < 4; ct++) {
#pragma unroll
      for (int dt = 0; dt < 4; dt++)
#pragma unroll
        for (int r = 0; r < 4; r++)
          Ol[ct * 16 + quad * 4 + r][dt * 16 + l16] = o[ct][dt][r];
      if (quad == 0) lsl[ct * 16 + l16] = ls[ct];
    }
  }
  __syncthreads();
  if (wave >= 2) {
#pragma unroll
    for (int ct = 0; ct < 4; ct++) {
#pragma unroll
      for (int dt = 0; dt < 4; dt++)
#pragma unroll
        for (int r = 0; r < 4; r++)
          Ol[ct * 16 + quad * 4 + r][dt * 16 + l16] += o[ct][dt][r];
      if (quad == 0) lsl[ct * 16 + l16] += ls[ct];
    }
  }
  __syncthreads();
  // normalized store: wave w covers rows w*16..+15; 4 lanes per row
  int row = wave * 16 + (lane >> 2);
  float inv = 1.0f / (lslA[row] + lslB[row]);
#pragma unroll
  for (int j = 0; j < 4; j++) {
    int col = (lane & 3) * 16 + j * 4;
    float4 a = *(const float4*)&OlA[row][col];
    float4 b = *(const float4*)&OlB[row][col];
    bf16x4 rv = (bf16x4){(__bf16)((a.x + b.x) * inv), (__bf16)((a.y + b.y) * inv),
                         (__bf16)((a.z + b.z) * inv), (__bf16)((a.w + b.w) * inv)};
    *(bf16x4*)&ctx[(size_t)(q0 + row) * DIMX + h * HD + col] = rv;
  }
}

extern "C" void kernel_launch(void* const* d_in, const int* in_sizes, int n_in,
                              void* d_out, int out_size, void* d_ws,
                              size_t ws_size, hipStream_t stream) {
  const float* x = (const float*)d_in[0];
  const float* wdkv = (const float*)d_in[1];
  const float* wuk = (const float*)d_in[2];
  const float* wuv = (const float*)d_in[3];
  const float* wuq = (const float*)d_in[4];
  const float* wo = (const float*)d_in[5];
  float* out = (float*)d_out;

  __bf16* ws = (__bf16*)d_ws;
  __bf16* x_bf = ws;                               // T*D
  __bf16* q = x_bf + (size_t)T_SEQ * DIMX;         // T*D (pre-scaled)
  __bf16* k = q + (size_t)T_SEQ * DIMX;            // T*D
  __bf16* vt = k + (size_t)T_SEQ * DIMX;           // D*T
  __bf16* ctx = vt + (size_t)T_SEQ * DIMX;         // T*D
  __bf16* ckv = ctx + (size_t)T_SEQ * DIMX;        // T*DLAT
  __bf16* wt_dkv = ckv + (size_t)T_SEQ * DLAT;     // DLAT x DIM
  __bf16* wt_uk = wt_dkv + (size_t)DLAT * DIMX;    // DIM x DLAT
  __bf16* wt_uv = wt_uk + (size_t)DIMX * DLAT;     // DIM x DLAT
  __bf16* wt_uq = wt_uv + (size_t)DIMX * DLAT;     // DIM x DIM
  __bf16* wt_o = wt_uq + (size_t)DIMX * DIMX;      // DIM x DIM

  dim3 blk(256);
  prep_kernel<<<dim3(2752), blk, 0, stream>>>(x, wdkv, wuk, wuv, wuq, wo, x_bf,
                                              wt_dkv, wt_uk, wt_uv, wt_uq, wt_o);
  gemm_a128<<<dim3(10, T_SEQ / 128), blk, 0, stream>>>(x_bf, wt_dkv, wt_uq,
                                                       ckv, q);
  gemm_kv128<<<dim3(16, T_SEQ / 128), blk, 0, stream>>>(ckv, wt_uk, wt_uv, k,
                                                        vt);
  mla_attn10<<<dim3(NH, 64), dim3(256), 0, stream>>>(q, k, vt, ctx);
  gemm_f128<<<dim3(DIMX / 128, T_SEQ / 128), blk, 0, stream>>>(ctx, wt_o, out);
}

// Round 8
// 200.449 us; speedup vs baseline: 1.3990x; 1.1896x over previous
//
#include <hip/hip_runtime.h>
#include <hip/hip_bf16.h>
#include <stdint.h>

#define T_SEQ 4096
#define DIMX 1024
#define NH 16
#define HD 64
#define DLAT 256

typedef __bf16 bf16x8 __attribute__((ext_vector_type(8)));
typedef __bf16 bf16x4 __attribute__((ext_vector_type(4)));
typedef float floatx4 __attribute__((ext_vector_type(4)));

#define MFMA(a, b, c) __builtin_amdgcn_mfma_f32_16x16x32_bf16(a, b, c, 0, 0, 0)

__device__ inline void gload_lds16(const __bf16* g, __bf16* l) {
  __builtin_amdgcn_global_load_lds(
      (const __attribute__((address_space(1))) uint32_t*)g,
      (__attribute__((address_space(3))) uint32_t*)l, 16, 0, 0);
}

// ---------- prep: x f32->bf16 convert + 5 weight transposes (round-8) -------
__global__ __launch_bounds__(256) void prep_kernel(
    const float* __restrict__ x, const float* __restrict__ wdkv,
    const float* __restrict__ wuk, const float* __restrict__ wuv,
    const float* __restrict__ wuq, const float* __restrict__ wo,
    __bf16* __restrict__ x_bf, __bf16* __restrict__ wt_dkv,
    __bf16* __restrict__ wt_uk, __bf16* __restrict__ wt_uv,
    __bf16* __restrict__ wt_uq, __bf16* __restrict__ wt_o) {
  int id = blockIdx.x;
  if (id < 2048) {
    int i = id * 256 + threadIdx.x;
    const float4* p = (const float4*)x;
    float4 a = p[2 * i], b = p[2 * i + 1];
    bf16x8 r = {(__bf16)a.x, (__bf16)a.y, (__bf16)a.z, (__bf16)a.w,
                (__bf16)b.x, (__bf16)b.y, (__bf16)b.z, (__bf16)b.w};
    *(bf16x8*)(x_bf + 8 * (size_t)i) = r;
    return;
  }
  int t = id - 2048;
  const float* in;
  __bf16* out;
  int R, C, lt;
  if (t < 64)       { in = wdkv; out = wt_dkv; R = 1024; C = 256;  lt = t; }
  else if (t < 128) { in = wuk;  out = wt_uk;  R = 256;  C = 1024; lt = t - 64; }
  else if (t < 192) { in = wuv;  out = wt_uv;  R = 256;  C = 1024; lt = t - 128; }
  else if (t < 448) { in = wuq;  out = wt_uq;  R = 1024; C = 1024; lt = t - 192; }
  else              { in = wo;   out = wt_o;   R = 1024; C = 1024; lt = t - 448; }
  __shared__ __bf16 tls[64][65];
  int tpr = C >> 6;
  int r0 = (lt / tpr) * 64, c0 = (lt % tpr) * 64;
  int tid = threadIdx.x;
#pragma unroll
  for (int i = 0; i < 16; i++) {
    int idx = tid + i * 256;
    int r = idx >> 6, c = idx & 63;
    tls[r][c] = (__bf16)in[(size_t)(r0 + r) * C + c0 + c];
  }
  __syncthreads();
#pragma unroll
  for (int i = 0; i < 16; i++) {
    int idx = tid + i * 256;
    int rr = idx & 63, cc = idx >> 6;
    out[(size_t)(c0 + cc) * R + r0 + rr] = tls[rr][cc];
  }
}

// ======== 128x128 GEMM, BK=64 via two independent BK=32 buffers =============
#define BUFE 4096  // 128*32

// ---------- gemm_a128: ckv = x@Wdkv' (bx<2), q = s*x@Wuq' (bx>=2) -----------
// q scale folds 1/8 (softmax scale) * log2(e) so attn can use exp2.
__global__ __launch_bounds__(256) void gemm_a128(const __bf16* __restrict__ A,
                                                 const __bf16* __restrict__ B1,
                                                 const __bf16* __restrict__ B2,
                                                 __bf16* __restrict__ C1,
                                                 __bf16* __restrict__ C2) {
  __shared__ __attribute__((aligned(16))) __bf16 Al[2][BUFE];
  __shared__ __attribute__((aligned(16))) __bf16 Bl[2][BUFE];
  int tid = threadIdx.x;
  int w = tid >> 6, lane = tid & 63;
  int quad = lane >> 4, l16 = lane & 15;
  int mw = w & 1, nw = w >> 1;
  int bx = blockIdx.x, m0 = blockIdx.y * 128;
  const __bf16* Bt;
  __bf16* C;
  int n0, N;
  float sc;
  if (bx < 2) { Bt = B1; C = C1; n0 = bx * 128; N = DLAT; sc = 1.0f; }
  else        { Bt = B2; C = C2; n0 = (bx - 2) * 128; N = DIMX;
                sc = 0.125f * 1.44269504088896340736f; }
  const int K = DIMX;
  int arow = w * 32 + (lane >> 2), acol = (lane & 3) << 3;

  floatx4 acc[4][4];
#pragma unroll
  for (int i = 0; i < 4; i++)
#pragma unroll
    for (int j = 0; j < 4; j++) acc[i][j] = (floatx4){0.f, 0.f, 0.f, 0.f};

  for (int k0 = 0; k0 < K; k0 += 64) {
#pragma unroll
    for (int kh = 0; kh < 2; kh++)
#pragma unroll
      for (int j = 0; j < 2; j++) {
        gload_lds16(A + (size_t)(m0 + arow + j * 16) * K + k0 + kh * 32 + acol,
                    &Al[kh][(w * 32 + j * 16) * 32]);
        gload_lds16(Bt + (size_t)(n0 + arow + j * 16) * K + k0 + kh * 32 + acol,
                    &Bl[kh][(w * 32 + j * 16) * 32]);
      }
    __syncthreads();
#pragma unroll
    for (int kh = 0; kh < 2; kh++) {
      bf16x8 af[4], bfr[4];
#pragma unroll
      for (int mt = 0; mt < 4; mt++)
        af[mt] =
            *(const bf16x8*)&Al[kh][(mw * 64 + mt * 16 + l16) * 32 + quad * 8];
#pragma unroll
      for (int nt = 0; nt < 4; nt++)
        bfr[nt] =
            *(const bf16x8*)&Bl[kh][(nw * 64 + nt * 16 + l16) * 32 + quad * 8];
#pragma unroll
      for (int mt = 0; mt < 4; mt++)
#pragma unroll
        for (int nt = 0; nt < 4; nt++)
          acc[mt][nt] = MFMA(af[mt], bfr[nt], acc[mt][nt]);
    }
    __syncthreads();
  }
#pragma unroll
  for (int mt = 0; mt < 4; mt++)
#pragma unroll
    for (int nt = 0; nt < 4; nt++)
#pragma unroll
      for (int r = 0; r < 4; r++) {
        int row = m0 + mw * 64 + mt * 16 + quad * 4 + r;
        int col = n0 + nw * 64 + nt * 16 + l16;
        C[(size_t)row * N + col] = (__bf16)(acc[mt][nt][r] * sc);
      }
}

// ---------- gemm_kv128: k = ckv@Wuk' (bx<8); vt = (ckv@Wuv')^T (bx>=8) ------
__global__ __launch_bounds__(256) void gemm_kv128(const __bf16* __restrict__ A,
                                                  const __bf16* __restrict__ Bk,
                                                  const __bf16* __restrict__ Bv,
                                                  __bf16* __restrict__ k,
                                                  __bf16* __restrict__ vt) {
  __shared__ __attribute__((aligned(16))) __bf16 Al[2][BUFE];
  __shared__ __attribute__((aligned(16))) __bf16 Bl[2][BUFE];
  __shared__ __attribute__((aligned(16))) __bf16 tw[4][64 * 72];
  int tid = threadIdx.x;
  int w = tid >> 6, lane = tid & 63;
  int quad = lane >> 4, l16 = lane & 15;
  int mw = w & 1, nw = w >> 1;
  int bx = blockIdx.x, m0 = blockIdx.y * 128;
  bool is_k = (bx < 8);
  const __bf16* Bt = is_k ? Bk : Bv;
  int n0 = (is_k ? bx : bx - 8) * 128;
  const int K = DLAT;
  int arow = w * 32 + (lane >> 2), acol = (lane & 3) << 3;

  floatx4 acc[4][4];
#pragma unroll
  for (int i = 0; i < 4; i++)
#pragma unroll
    for (int j = 0; j < 4; j++) acc[i][j] = (floatx4){0.f, 0.f, 0.f, 0.f};

  for (int k0 = 0; k0 < K; k0 += 64) {
#pragma unroll
    for (int kh = 0; kh < 2; kh++)
#pragma unroll
      for (int j = 0; j < 2; j++) {
        gload_lds16(A + (size_t)(m0 + arow + j * 16) * K + k0 + kh * 32 + acol,
                    &Al[kh][(w * 32 + j * 16) * 32]);
        gload_lds16(Bt + (size_t)(n0 + arow + j * 16) * K + k0 + kh * 32 + acol,
                    &Bl[kh][(w * 32 + j * 16) * 32]);
      }
    __syncthreads();
#pragma unroll
    for (int kh = 0; kh < 2; kh++) {
      bf16x8 af[4], bfr[4];
#pragma unroll
      for (int mt = 0; mt < 4; mt++)
        af[mt] =
            *(const bf16x8*)&Al[kh][(mw * 64 + mt * 16 + l16) * 32 + quad * 8];
#pragma unroll
      for (int nt = 0; nt < 4; nt++)
        bfr[nt] =
            *(const bf16x8*)&Bl[kh][(nw * 64 + nt * 16 + l16) * 32 + quad * 8];
#pragma unroll
      for (int mt = 0; mt < 4; mt++)
#pragma unroll
        for (int nt = 0; nt < 4; nt++)
          acc[mt][nt] = MFMA(af[mt], bfr[nt], acc[mt][nt]);
    }
    __syncthreads();
  }
  if (is_k) {
#pragma unroll
    for (int mt = 0; mt < 4; mt++)
#pragma unroll
      for (int nt = 0; nt < 4; nt++)
#pragma unroll
        for (int r = 0; r < 4; r++) {
          int row = m0 + mw * 64 + mt * 16 + quad * 4 + r;
          int col = n0 + nw * 64 + nt * 16 + l16;
          k[(size_t)row * DIMX + col] = (__bf16)acc[mt][nt][r];
        }
  } else {
#pragma unroll
    for (int mt = 0; mt < 4; mt++)
#pragma unroll
      for (int nt = 0; nt < 4; nt++)
#pragma unroll
        for (int r = 0; r < 4; r++)
          tw[w][(nt * 16 + l16) * 72 + mt * 16 + quad * 4 + r] =
              (__bf16)acc[mt][nt][r];
    int cbase = lane >> 3, chunk = lane & 7;
#pragma unroll
    for (int i = 0; i < 8; i++) {
      int c = cbase + i * 8;
      bf16x8 v8 = *(const bf16x8*)&tw[w][c * 72 + chunk * 8];
      *(bf16x8*)&vt[(size_t)(n0 + nw * 64 + c) * T_SEQ + m0 + mw * 64 +
                    chunk * 8] = v8;
    }
  }
}

// ---------- gemm_f128: out(f32) = ctx @ Wo' -------------------------------
__global__ __launch_bounds__(256) void gemm_f128(const __bf16* __restrict__ A,
                                                 const __bf16* __restrict__ Bt,
                                                 float* __restrict__ C) {
  __shared__ __attribute__((aligned(16))) __bf16 Al[2][BUFE];
  __shared__ __attribute__((aligned(16))) __bf16 Bl[2][BUFE];
  int tid = threadIdx.x;
  int w = tid >> 6, lane = tid & 63;
  int quad = lane >> 4, l16 = lane & 15;
  int mw = w & 1, nw = w >> 1;
  int n0 = blockIdx.x * 128, m0 = blockIdx.y * 128;
  const int K = DIMX, N = DIMX;
  int arow = w * 32 + (lane >> 2), acol = (lane & 3) << 3;

  floatx4 acc[4][4];
#pragma unroll
  for (int i = 0; i < 4; i++)
#pragma unroll
    for (int j = 0; j < 4; j++) acc[i][j] = (floatx4){0.f, 0.f, 0.f, 0.f};

  for (int k0 = 0; k0 < K; k0 += 64) {
#pragma unroll
    for (int kh = 0; kh < 2; kh++)
#pragma unroll
      for (int j = 0; j < 2; j++) {
        gload_lds16(A + (size_t)(m0 + arow + j * 16) * K + k0 + kh * 32 + acol,
                    &Al[kh][(w * 32 + j * 16) * 32]);
        gload_lds16(Bt + (size_t)(n0 + arow + j * 16) * K + k0 + kh * 32 + acol,
                    &Bl[kh][(w * 32 + j * 16) * 32]);
      }
    __syncthreads();
#pragma unroll
    for (int kh = 0; kh < 2; kh++) {
      bf16x8 af[4], bfr[4];
#pragma unroll
      for (int mt = 0; mt < 4; mt++)
        af[mt] =
            *(const bf16x8*)&Al[kh][(mw * 64 + mt * 16 + l16) * 32 + quad * 8];
#pragma unroll
      for (int nt = 0; nt < 4; nt++)
        bfr[nt] =
            *(const bf16x8*)&Bl[kh][(nw * 64 + nt * 16 + l16) * 32 + quad * 8];
#pragma unroll
      for (int mt = 0; mt < 4; mt++)
#pragma unroll
        for (int nt = 0; nt < 4; nt++)
          acc[mt][nt] = MFMA(af[mt], bfr[nt], acc[mt][nt]);
    }
    __syncthreads();
  }
#pragma unroll
  for (int mt = 0; mt < 4; mt++)
#pragma unroll
    for (int nt = 0; nt < 4; nt++)
#pragma unroll
      for (int r = 0; r < 4; r++) {
        int row = m0 + mw * 64 + mt * 16 + quad * 4 + r;
        int col = n0 + nw * 64 + nt * 16 + l16;
        C[(size_t)row * N + col] = acc[mt][nt][r];
      }
}

// ---------- flash attention v11: v6 loop + unpaired 1024-block global LPT ---
// r4 retried with the ONLY change being dispatch order: dim3(NH, 64) with
// heads fastest and qt = 63 - blockIdx.y, so all 16 heads' cost-64 blocks
// dispatch first (true global LPT; r4's per-head LPT left a 34us tail).
// Inner iteration byte-identical to validated v6 (r2). 3 blocks/CU resident.
#define PST 72
__global__ __launch_bounds__(256, 3) void mla_attn11(
    const __bf16* __restrict__ Q, const __bf16* __restrict__ Kg,
    const __bf16* __restrict__ Vt, __bf16* __restrict__ ctx) {
  __shared__ __attribute__((aligned(16))) __bf16 Kl[2][64 * 64];
  __shared__ __attribute__((aligned(16))) __bf16 Vl[2][64 * 64];
  __shared__ __attribute__((aligned(16))) __bf16 Pl[64 * PST];
  int tid = threadIdx.x;
  int wave = tid >> 6, lane = tid & 63;
  int quad = lane >> 4, l16 = lane & 15;
  int h = blockIdx.x;        // heads vary fastest in dispatch order
  int qt = 63 - blockIdx.y;  // global LPT: all large blocks dispatch first
  int q0 = qt * 64;
  int srow = tid >> 3, pos = tid & 7;  // srow 0..31, rows srow and srow+32
  int gco = pos << 3;
  int sw = (pos ^ (srow & 7)) << 3;
  int swr = srow * 64 + sw;
  int fr = (wave * 16 + l16) * PST;
  int c0s = ((quad ^ (l16 & 7)) << 3);
  int c1s = (((4 + quad) ^ (l16 & 7)) << 3);

  // stage Q (2 rows/thread) + K/V tile 0
  *(bf16x8*)&Pl[srow * PST + gco] =
      *(const bf16x8*)&Q[(size_t)(q0 + srow) * DIMX + h * HD + gco];
  *(bf16x8*)&Pl[(srow + 32) * PST + gco] =
      *(const bf16x8*)&Q[(size_t)(q0 + srow + 32) * DIMX + h * HD + gco];
  *(bf16x8*)&Kl[0][swr] =
      *(const bf16x8*)&Kg[(size_t)srow * DIMX + h * HD + gco];
  *(bf16x8*)&Kl[0][swr + 2048] =
      *(const bf16x8*)&Kg[(size_t)(srow + 32) * DIMX + h * HD + gco];
  *(bf16x8*)&Vl[0][swr] =
      *(const bf16x8*)&Vt[(size_t)(h * HD + srow) * T_SEQ + gco];
  *(bf16x8*)&Vl[0][swr + 2048] =
      *(const bf16x8*)&Vt[(size_t)(h * HD + srow + 32) * T_SEQ + gco];
  __syncthreads();
  bf16x8 qf0 = *(const bf16x8*)&Pl[fr + quad * 8];
  bf16x8 qf1 = *(const bf16x8*)&Pl[fr + 32 + quad * 8];

  floatx4 o[4];
  float lsum = 0.f;
#pragma unroll
  for (int i = 0; i < 4; i++) o[i] = (floatx4){0.f, 0.f, 0.f, 0.f};

  for (int kt = 0; kt <= qt; kt++) {
    int cur = kt & 1, nxt = cur ^ 1;
    bool pre = (kt < qt);
    bf16x8 kp0, kp1, vp0, vp1;
    if (pre) {
      int k0n = (kt + 1) * 64;
      kp0 = *(const bf16x8*)&Kg[(size_t)(k0n + srow) * DIMX + h * HD + gco];
      kp1 = *(const bf16x8*)&Kg[(size_t)(k0n + srow + 32) * DIMX + h * HD + gco];
      vp0 = *(const bf16x8*)&Vt[(size_t)(h * HD + srow) * T_SEQ + k0n + gco];
      vp1 = *(const bf16x8*)&Vt[(size_t)(h * HD + srow + 32) * T_SEQ + k0n + gco];
    }
    const __bf16* Kc = Kl[cur];
    const __bf16* Vc = Vl[cur];
    floatx4 s[4];
    __builtin_amdgcn_s_setprio(1);
#pragma unroll
    for (int ct = 0; ct < 4; ct++) {
      int rb = (ct * 16 + l16) * 64;
      bf16x8 kf0 = *(const bf16x8*)&Kc[rb + c0s];
      bf16x8 kf1 = *(const bf16x8*)&Kc[rb + c1s];
      floatx4 z = (floatx4){0.f, 0.f, 0.f, 0.f};
      z = MFMA(kf0, qf0, z);  // swapped: lane holds P[q=l16][k=ct*16+quad*4+r]
      z = MFMA(kf1, qf1, z);
      s[ct] = z;
    }
    __builtin_amdgcn_s_setprio(0);
    bool diag = (kt == qt);
#pragma unroll
    for (int ct = 0; ct < 4; ct++) {
      float p0[4];
#pragma unroll
      for (int r = 0; r < 4; r++) {
        float p = __builtin_amdgcn_exp2f(s[ct][r]);
        if (diag && (ct * 16 + quad * 4 + r > wave * 16 + l16)) p = 0.f;
        lsum += p;
        p0[r] = p;
      }
      bf16x4 pk = {(__bf16)p0[0], (__bf16)p0[1], (__bf16)p0[2], (__bf16)p0[3]};
      *(bf16x4*)&Pl[(wave * 16 + l16) * PST + ct * 16 + quad * 4] = pk;
    }
    bf16x8 pf0 = *(const bf16x8*)&Pl[fr + quad * 8];
    bf16x8 pf1 = *(const bf16x8*)&Pl[fr + 32 + quad * 8];
    __builtin_amdgcn_s_setprio(1);
#pragma unroll
    for (int dt = 0; dt < 4; dt++) {
      int rb = (dt * 16 + l16) * 64;
      bf16x8 vf0 = *(const bf16x8*)&Vc[rb + c0s];
      bf16x8 vf1 = *(const bf16x8*)&Vc[rb + c1s];
      o[dt] = MFMA(pf0, vf0, o[dt]);
      o[dt] = MFMA(pf1, vf1, o[dt]);
    }
    __builtin_amdgcn_s_setprio(0);
    if (pre) {
      *(bf16x8*)&Kl[nxt][swr] = kp0;
      *(bf16x8*)&Kl[nxt][swr + 2048] = kp1;
      *(bf16x8*)&Vl[nxt][swr] = vp0;
      *(bf16x8*)&Vl[nxt][swr + 2048] = vp1;
    }
    __syncthreads();
  }

  // row sums: lane holds partial for q=l16 over its k-subset; reduce quads.
  lsum += __shfl_xor(lsum, 16, 64);
  lsum += __shfl_xor(lsum, 32, 64);
  float inv[4];
#pragma unroll
  for (int r = 0; r < 4; r++) inv[r] = 1.0f / __shfl(lsum, quad * 4 + r, 16);

#pragma unroll
  for (int dt = 0; dt < 4; dt++)
#pragma unroll
    for (int r = 0; r < 4; r++) {
      float val = o[dt][r] * inv[r];
      int row = q0 + wave * 16 + quad * 4 + r;
      int col = h * HD + dt * 16 + l16;
      ctx[(size_t)row * DIMX + col] = (__bf16)val;
    }
}

extern "C" void kernel_launch(void* const* d_in, const int* in_sizes, int n_in,
                              void* d_out, int out_size, void* d_ws,
                              size_t ws_size, hipStream_t stream) {
  const float* x = (const float*)d_in[0];
  const float* wdkv = (const float*)d_in[1];
  const float* wuk = (const float*)d_in[2];
  const float* wuv = (const float*)d_in[3];
  const float* wuq = (const float*)d_in[4];
  const float* wo = (const float*)d_in[5];
  float* out = (float*)d_out;

  __bf16* ws = (__bf16*)d_ws;
  __bf16* x_bf = ws;                               // T*D
  __bf16* q = x_bf + (size_t)T_SEQ * DIMX;         // T*D (pre-scaled)
  __bf16* k = q + (size_t)T_SEQ * DIMX;            // T*D
  __bf16* vt = k + (size_t)T_SEQ * DIMX;           // D*T
  __bf16* ctx = vt + (size_t)T_SEQ * DIMX;         // T*D
  __bf16* ckv = ctx + (size_t)T_SEQ * DIMX;        // T*DLAT
  __bf16* wt_dkv = ckv + (size_t)T_SEQ * DLAT;     // DLAT x DIM
  __bf16* wt_uk = wt_dkv + (size_t)DLAT * DIMX;    // DIM x DLAT
  __bf16* wt_uv = wt_uk + (size_t)DIMX * DLAT;     // DIM x DLAT
  __bf16* wt_uq = wt_uv + (size_t)DIMX * DLAT;     // DIM x DIM
  __bf16* wt_o = wt_uq + (size_t)DIMX * DIMX;      // DIM x DIM

  dim3 blk(256);
  prep_kernel<<<dim3(2752), blk, 0, stream>>>(x, wdkv, wuk, wuv, wuq, wo, x_bf,
                                              wt_dkv, wt_uk, wt_uv, wt_uq, wt_o);
  gemm_a128<<<dim3(10, T_SEQ / 128), blk, 0, stream>>>(x_bf, wt_dkv, wt_uq,
                                                       ckv, q);
  gemm_kv128<<<dim3(16, T_SEQ / 128), blk, 0, stream>>>(ckv, wt_uk, wt_uv, k,
                                                        vt);
  mla_attn11<<<dim3(NH, 64), dim3(256), 0, stream>>>(q, k, vt, ctx);
  gemm_f128<<<dim3(DIMX / 128, T_SEQ / 128), blk, 0, stream>>>(ctx, wt_o, out);
}

// Round 9
// 189.433 us; speedup vs baseline: 1.4804x; 1.0582x over previous
//
#include <hip/hip_runtime.h>
#include <hip/hip_bf16.h>
#include <stdint.h>

#define T_SEQ 4096
#define DIMX 1024
#define NH 16
#define HD 64
#define DLAT 256

typedef __bf16 bf16x8 __attribute__((ext_vector_type(8)));
typedef __bf16 bf16x4 __attribute__((ext_vector_type(4)));
typedef float floatx4 __attribute__((ext_vector_type(4)));

#define MFMA(a, b, c) __builtin_amdgcn_mfma_f32_16x16x32_bf16(a, b, c, 0, 0, 0)

__device__ inline void gload_lds16(const __bf16* g, __bf16* l) {
  __builtin_amdgcn_global_load_lds(
      (const __attribute__((address_space(1))) uint32_t*)g,
      (__attribute__((address_space(3))) uint32_t*)l, 16, 0, 0);
}

// ---------- prep: x f32->bf16 convert + 5 weight transposes (round-8) -------
__global__ __launch_bounds__(256) void prep_kernel(
    const float* __restrict__ x, const float* __restrict__ wdkv,
    const float* __restrict__ wuk, const float* __restrict__ wuv,
    const float* __restrict__ wuq, const float* __restrict__ wo,
    __bf16* __restrict__ x_bf, __bf16* __restrict__ wt_dkv,
    __bf16* __restrict__ wt_uk, __bf16* __restrict__ wt_uv,
    __bf16* __restrict__ wt_uq, __bf16* __restrict__ wt_o) {
  int id = blockIdx.x;
  if (id < 2048) {
    int i = id * 256 + threadIdx.x;
    const float4* p = (const float4*)x;
    float4 a = p[2 * i], b = p[2 * i + 1];
    bf16x8 r = {(__bf16)a.x, (__bf16)a.y, (__bf16)a.z, (__bf16)a.w,
                (__bf16)b.x, (__bf16)b.y, (__bf16)b.z, (__bf16)b.w};
    *(bf16x8*)(x_bf + 8 * (size_t)i) = r;
    return;
  }
  int t = id - 2048;
  const float* in;
  __bf16* out;
  int R, C, lt;
  if (t < 64)       { in = wdkv; out = wt_dkv; R = 1024; C = 256;  lt = t; }
  else if (t < 128) { in = wuk;  out = wt_uk;  R = 256;  C = 1024; lt = t - 64; }
  else if (t < 192) { in = wuv;  out = wt_uv;  R = 256;  C = 1024; lt = t - 128; }
  else if (t < 448) { in = wuq;  out = wt_uq;  R = 1024; C = 1024; lt = t - 192; }
  else              { in = wo;   out = wt_o;   R = 1024; C = 1024; lt = t - 448; }
  __shared__ __bf16 tls[64][65];
  int tpr = C >> 6;
  int r0 = (lt / tpr) * 64, c0 = (lt % tpr) * 64;
  int tid = threadIdx.x;
#pragma unroll
  for (int i = 0; i < 16; i++) {
    int idx = tid + i * 256;
    int r = idx >> 6, c = idx & 63;
    tls[r][c] = (__bf16)in[(size_t)(r0 + r) * C + c0 + c];
  }
  __syncthreads();
#pragma unroll
  for (int i = 0; i < 16; i++) {
    int idx = tid + i * 256;
    int rr = idx & 63, cc = idx >> 6;
    out[(size_t)(c0 + cc) * R + r0 + rr] = tls[rr][cc];
  }
}

// ======== GEMM tiles ========================================================
#define BUFE 4096   // 128 rows x 32 cols (A tile per kh)
#define BUFEB 2048  // 64 rows x 32 cols (B tile per kh, 128x64 kernels)

// ---------- gemm_a64: 128x64 tiles. ckv = x@Wdkv' (bx<4), q = s*x@Wuq' ------
// 640 blocks (2.5/CU) vs 320 at 128x128: residency was the GEMM bottleneck.
// q scale folds 1/8 (softmax scale) * log2(e) so attn can use exp2.
__global__ __launch_bounds__(256) void gemm_a64(const __bf16* __restrict__ A,
                                                const __bf16* __restrict__ B1,
                                                const __bf16* __restrict__ B2,
                                                __bf16* __restrict__ C1,
                                                __bf16* __restrict__ C2) {
  __shared__ __attribute__((aligned(16))) __bf16 Al[2][BUFE];
  __shared__ __attribute__((aligned(16))) __bf16 Bl[2][BUFEB];
  int tid = threadIdx.x;
  int w = tid >> 6, lane = tid & 63;
  int quad = lane >> 4, l16 = lane & 15;
  int mw = w & 1, nw = w >> 1;
  int bx = blockIdx.x, m0 = blockIdx.y * 128;
  const __bf16* Bt;
  __bf16* C;
  int n0, N;
  float sc;
  if (bx < 4) { Bt = B1; C = C1; n0 = bx * 64; N = DLAT; sc = 1.0f; }
  else        { Bt = B2; C = C2; n0 = (bx - 4) * 64; N = DIMX;
                sc = 0.125f * 1.44269504088896340736f; }
  const int K = DIMX;
  int arow = w * 32 + (lane >> 2), acol = (lane & 3) << 3;
  int brow = w * 16 + (lane >> 2);

  floatx4 acc[4][2];
#pragma unroll
  for (int i = 0; i < 4; i++)
#pragma unroll
    for (int j = 0; j < 2; j++) acc[i][j] = (floatx4){0.f, 0.f, 0.f, 0.f};

  for (int k0 = 0; k0 < K; k0 += 64) {
#pragma unroll
    for (int kh = 0; kh < 2; kh++) {
#pragma unroll
      for (int j = 0; j < 2; j++)
        gload_lds16(A + (size_t)(m0 + arow + j * 16) * K + k0 + kh * 32 + acol,
                    &Al[kh][(w * 32 + j * 16) * 32]);
      gload_lds16(Bt + (size_t)(n0 + brow) * K + k0 + kh * 32 + acol,
                  &Bl[kh][(w * 16) * 32]);
    }
    __syncthreads();
#pragma unroll
    for (int kh = 0; kh < 2; kh++) {
      bf16x8 af[4], bfr[2];
#pragma unroll
      for (int mt = 0; mt < 4; mt++)
        af[mt] =
            *(const bf16x8*)&Al[kh][(mw * 64 + mt * 16 + l16) * 32 + quad * 8];
#pragma unroll
      for (int nt = 0; nt < 2; nt++)
        bfr[nt] =
            *(const bf16x8*)&Bl[kh][(nw * 32 + nt * 16 + l16) * 32 + quad * 8];
#pragma unroll
      for (int mt = 0; mt < 4; mt++)
#pragma unroll
        for (int nt = 0; nt < 2; nt++)
          acc[mt][nt] = MFMA(af[mt], bfr[nt], acc[mt][nt]);
    }
    __syncthreads();
  }
#pragma unroll
  for (int mt = 0; mt < 4; mt++)
#pragma unroll
    for (int nt = 0; nt < 2; nt++)
#pragma unroll
      for (int r = 0; r < 4; r++) {
        int row = m0 + mw * 64 + mt * 16 + quad * 4 + r;
        int col = n0 + nw * 32 + nt * 16 + l16;
        C[(size_t)row * N + col] = (__bf16)(acc[mt][nt][r] * sc);
      }
}

// ---------- gemm_kv128: k = ckv@Wuk' (bx<8); vt = (ckv@Wuv')^T (bx>=8) ------
__global__ __launch_bounds__(256) void gemm_kv128(const __bf16* __restrict__ A,
                                                  const __bf16* __restrict__ Bk,
                                                  const __bf16* __restrict__ Bv,
                                                  __bf16* __restrict__ k,
                                                  __bf16* __restrict__ vt) {
  __shared__ __attribute__((aligned(16))) __bf16 Al[2][BUFE];
  __shared__ __attribute__((aligned(16))) __bf16 Bl[2][BUFE];
  __shared__ __attribute__((aligned(16))) __bf16 tw[4][64 * 72];
  int tid = threadIdx.x;
  int w = tid >> 6, lane = tid & 63;
  int quad = lane >> 4, l16 = lane & 15;
  int mw = w & 1, nw = w >> 1;
  int bx = blockIdx.x, m0 = blockIdx.y * 128;
  bool is_k = (bx < 8);
  const __bf16* Bt = is_k ? Bk : Bv;
  int n0 = (is_k ? bx : bx - 8) * 128;
  const int K = DLAT;
  int arow = w * 32 + (lane >> 2), acol = (lane & 3) << 3;

  floatx4 acc[4][4];
#pragma unroll
  for (int i = 0; i < 4; i++)
#pragma unroll
    for (int j = 0; j < 4; j++) acc[i][j] = (floatx4){0.f, 0.f, 0.f, 0.f};

  for (int k0 = 0; k0 < K; k0 += 64) {
#pragma unroll
    for (int kh = 0; kh < 2; kh++)
#pragma unroll
      for (int j = 0; j < 2; j++) {
        gload_lds16(A + (size_t)(m0 + arow + j * 16) * K + k0 + kh * 32 + acol,
                    &Al[kh][(w * 32 + j * 16) * 32]);
        gload_lds16(Bt + (size_t)(n0 + arow + j * 16) * K + k0 + kh * 32 + acol,
                    &Bl[kh][(w * 32 + j * 16) * 32]);
      }
    __syncthreads();
#pragma unroll
    for (int kh = 0; kh < 2; kh++) {
      bf16x8 af[4], bfr[4];
#pragma unroll
      for (int mt = 0; mt < 4; mt++)
        af[mt] =
            *(const bf16x8*)&Al[kh][(mw * 64 + mt * 16 + l16) * 32 + quad * 8];
#pragma unroll
      for (int nt = 0; nt < 4; nt++)
        bfr[nt] =
            *(const bf16x8*)&Bl[kh][(nw * 64 + nt * 16 + l16) * 32 + quad * 8];
#pragma unroll
      for (int mt = 0; mt < 4; mt++)
#pragma unroll
        for (int nt = 0; nt < 4; nt++)
          acc[mt][nt] = MFMA(af[mt], bfr[nt], acc[mt][nt]);
    }
    __syncthreads();
  }
  if (is_k) {
#pragma unroll
    for (int mt = 0; mt < 4; mt++)
#pragma unroll
      for (int nt = 0; nt < 4; nt++)
#pragma unroll
        for (int r = 0; r < 4; r++) {
          int row = m0 + mw * 64 + mt * 16 + quad * 4 + r;
          int col = n0 + nw * 64 + nt * 16 + l16;
          k[(size_t)row * DIMX + col] = (__bf16)acc[mt][nt][r];
        }
  } else {
#pragma unroll
    for (int mt = 0; mt < 4; mt++)
#pragma unroll
      for (int nt = 0; nt < 4; nt++)
#pragma unroll
        for (int r = 0; r < 4; r++)
          tw[w][(nt * 16 + l16) * 72 + mt * 16 + quad * 4 + r] =
              (__bf16)acc[mt][nt][r];
    int cbase = lane >> 3, chunk = lane & 7;
#pragma unroll
    for (int i = 0; i < 8; i++) {
      int c = cbase + i * 8;
      bf16x8 v8 = *(const bf16x8*)&tw[w][c * 72 + chunk * 8];
      *(bf16x8*)&vt[(size_t)(n0 + nw * 64 + c) * T_SEQ + m0 + mw * 64 +
                    chunk * 8] = v8;
    }
  }
}

// ---------- gemm_f64: out(f32) = ctx @ Wo', 128x64 tiles (512 blocks) ------
__global__ __launch_bounds__(256) void gemm_f64(const __bf16* __restrict__ A,
                                                const __bf16* __restrict__ Bt,
                                                float* __restrict__ C) {
  __shared__ __attribute__((aligned(16))) __bf16 Al[2][BUFE];
  __shared__ __attribute__((aligned(16))) __bf16 Bl[2][BUFEB];
  int tid = threadIdx.x;
  int w = tid >> 6, lane = tid & 63;
  int quad = lane >> 4, l16 = lane & 15;
  int mw = w & 1, nw = w >> 1;
  int n0 = blockIdx.x * 64, m0 = blockIdx.y * 128;
  const int K = DIMX, N = DIMX;
  int arow = w * 32 + (lane >> 2), acol = (lane & 3) << 3;
  int brow = w * 16 + (lane >> 2);

  floatx4 acc[4][2];
#pragma unroll
  for (int i = 0; i < 4; i++)
#pragma unroll
    for (int j = 0; j < 2; j++) acc[i][j] = (floatx4){0.f, 0.f, 0.f, 0.f};

  for (int k0 = 0; k0 < K; k0 += 64) {
#pragma unroll
    for (int kh = 0; kh < 2; kh++) {
#pragma unroll
      for (int j = 0; j < 2; j++)
        gload_lds16(A + (size_t)(m0 + arow + j * 16) * K + k0 + kh * 32 + acol,
                    &Al[kh][(w * 32 + j * 16) * 32]);
      gload_lds16(Bt + (size_t)(n0 + brow) * K + k0 + kh * 32 + acol,
                  &Bl[kh][(w * 16) * 32]);
    }
    __syncthreads();
#pragma unroll
    for (int kh = 0; kh < 2; kh++) {
      bf16x8 af[4], bfr[2];
#pragma unroll
      for (int mt = 0; mt < 4; mt++)
        af[mt] =
            *(const bf16x8*)&Al[kh][(mw * 64 + mt * 16 + l16) * 32 + quad * 8];
#pragma unroll
      for (int nt = 0; nt < 2; nt++)
        bfr[nt] =
            *(const bf16x8*)&Bl[kh][(nw * 32 + nt * 16 + l16) * 32 + quad * 8];
#pragma unroll
      for (int mt = 0; mt < 4; mt++)
#pragma unroll
        for (int nt = 0; nt < 2; nt++)
          acc[mt][nt] = MFMA(af[mt], bfr[nt], acc[mt][nt]);
    }
    __syncthreads();
  }
#pragma unroll
  for (int mt = 0; mt < 4; mt++)
#pragma unroll
    for (int nt = 0; nt < 2; nt++)
#pragma unroll
      for (int r = 0; r < 4; r++) {
        int row = m0 + mw * 64 + mt * 16 + quad * 4 + r;
        int col = n0 + nw * 32 + nt * 16 + l16;
        C[(size_t)row * N + col] = acc[mt][nt][r];
      }
}

// ---------- flash attention v11 (validated r8: 68.5us, best) ----------------
#define PST 72
__global__ __launch_bounds__(256, 3) void mla_attn11(
    const __bf16* __restrict__ Q, const __bf16* __restrict__ Kg,
    const __bf16* __restrict__ Vt, __bf16* __restrict__ ctx) {
  __shared__ __attribute__((aligned(16))) __bf16 Kl[2][64 * 64];
  __shared__ __attribute__((aligned(16))) __bf16 Vl[2][64 * 64];
  __shared__ __attribute__((aligned(16))) __bf16 Pl[64 * PST];
  int tid = threadIdx.x;
  int wave = tid >> 6, lane = tid & 63;
  int quad = lane >> 4, l16 = lane & 15;
  int h = blockIdx.x;        // heads vary fastest in dispatch order
  int qt = 63 - blockIdx.y;  // global LPT: all large blocks dispatch first
  int q0 = qt * 64;
  int srow = tid >> 3, pos = tid & 7;  // srow 0..31, rows srow and srow+32
  int gco = pos << 3;
  int sw = (pos ^ (srow & 7)) << 3;
  int swr = srow * 64 + sw;
  int fr = (wave * 16 + l16) * PST;
  int c0s = ((quad ^ (l16 & 7)) << 3);
  int c1s = (((4 + quad) ^ (l16 & 7)) << 3);

  // stage Q (2 rows/thread) + K/V tile 0
  *(bf16x8*)&Pl[srow * PST + gco] =
      *(const bf16x8*)&Q[(size_t)(q0 + srow) * DIMX + h * HD + gco];
  *(bf16x8*)&Pl[(srow + 32) * PST + gco] =
      *(const bf16x8*)&Q[(size_t)(q0 + srow + 32) * DIMX + h * HD + gco];
  *(bf16x8*)&Kl[0][swr] =
      *(const bf16x8*)&Kg[(size_t)srow * DIMX + h * HD + gco];
  *(bf16x8*)&Kl[0][swr + 2048] =
      *(const bf16x8*)&Kg[(size_t)(srow + 32) * DIMX + h * HD + gco];
  *(bf16x8*)&Vl[0][swr] =
      *(const bf16x8*)&Vt[(size_t)(h * HD + srow) * T_SEQ + gco];
  *(bf16x8*)&Vl[0][swr + 2048] =
      *(const bf16x8*)&Vt[(size_t)(h * HD + srow + 32) * T_SEQ + gco];
  __syncthreads();
  bf16x8 qf0 = *(const bf16x8*)&Pl[fr + quad * 8];
  bf16x8 qf1 = *(const bf16x8*)&Pl[fr + 32 + quad * 8];

  floatx4 o[4];
  float lsum = 0.f;
#pragma unroll
  for (int i = 0; i < 4; i++) o[i] = (floatx4){0.f, 0.f, 0.f, 0.f};

  for (int kt = 0; kt <= qt; kt++) {
    int cur = kt & 1, nxt = cur ^ 1;
    bool pre = (kt < qt);
    bf16x8 kp0, kp1, vp0, vp1;
    if (pre) {
      int k0n = (kt + 1) * 64;
      kp0 = *(const bf16x8*)&Kg[(size_t)(k0n + srow) * DIMX + h * HD + gco];
      kp1 = *(const bf16x8*)&Kg[(size_t)(k0n + srow + 32) * DIMX + h * HD + gco];
      vp0 = *(const bf16x8*)&Vt[(size_t)(h * HD + srow) * T_SEQ + k0n + gco];
      vp1 = *(const bf16x8*)&Vt[(size_t)(h * HD + srow + 32) * T_SEQ + k0n + gco];
    }
    const __bf16* Kc = Kl[cur];
    const __bf16* Vc = Vl[cur];
    floatx4 s[4];
    __builtin_amdgcn_s_setprio(1);
#pragma unroll
    for (int ct = 0; ct < 4; ct++) {
      int rb = (ct * 16 + l16) * 64;
      bf16x8 kf0 = *(const bf16x8*)&Kc[rb + c0s];
      bf16x8 kf1 = *(const bf16x8*)&Kc[rb + c1s];
      floatx4 z = (floatx4){0.f, 0.f, 0.f, 0.f};
      z = MFMA(kf0, qf0, z);  // swapped: lane holds P[q=l16][k=ct*16+quad*4+r]
      z = MFMA(kf1, qf1, z);
      s[ct] = z;
    }
    __builtin_amdgcn_s_setprio(0);
    bool diag = (kt == qt);
#pragma unroll
    for (int ct = 0; ct < 4; ct++) {
      float p0[4];
#pragma unroll
      for (int r = 0; r < 4; r++) {
        float p = __builtin_amdgcn_exp2f(s[ct][r]);
        if (diag && (ct * 16 + quad * 4 + r > wave * 16 + l16)) p = 0.f;
        lsum += p;
        p0[r] = p;
      }
      bf16x4 pk = {(__bf16)p0[0], (__bf16)p0[1], (__bf16)p0[2], (__bf16)p0[3]};
      *(bf16x4*)&Pl[(wave * 16 + l16) * PST + ct * 16 + quad * 4] = pk;
    }
    bf16x8 pf0 = *(const bf16x8*)&Pl[fr + quad * 8];
    bf16x8 pf1 = *(const bf16x8*)&Pl[fr + 32 + quad * 8];
    __builtin_amdgcn_s_setprio(1);
#pragma unroll
    for (int dt = 0; dt < 4; dt++) {
      int rb = (dt * 16 + l16) * 64;
      bf16x8 vf0 = *(const bf16x8*)&Vc[rb + c0s];
      bf16x8 vf1 = *(const bf16x8*)&Vc[rb + c1s];
      o[dt] = MFMA(pf0, vf0, o[dt]);
      o[dt] = MFMA(pf1, vf1, o[dt]);
    }
    __builtin_amdgcn_s_setprio(0);
    if (pre) {
      *(bf16x8*)&Kl[nxt][swr] = kp0;
      *(bf16x8*)&Kl[nxt][swr + 2048] = kp1;
      *(bf16x8*)&Vl[nxt][swr] = vp0;
      *(bf16x8*)&Vl[nxt][swr + 2048] = vp1;
    }
    __syncthreads();
  }

  // row sums: lane holds partial for q=l16 over its k-subset; reduce quads.
  lsum += __shfl_xor(lsum, 16, 64);
  lsum += __shfl_xor(lsum, 32, 64);
  float inv[4];
#pragma unroll
  for (int r = 0; r < 4; r++) inv[r] = 1.0f / __shfl(lsum, quad * 4 + r, 16);

#pragma unroll
  for (int dt = 0; dt < 4; dt++)
#pragma unroll
    for (int r = 0; r < 4; r++) {
      float val = o[dt][r] * inv[r];
      int row = q0 + wave * 16 + quad * 4 + r;
      int col = h * HD + dt * 16 + l16;
      ctx[(size_t)row * DIMX + col] = (__bf16)val;
    }
}

extern "C" void kernel_launch(void* const* d_in, const int* in_sizes, int n_in,
                              void* d_out, int out_size, void* d_ws,
                              size_t ws_size, hipStream_t stream) {
  const float* x = (const float*)d_in[0];
  const float* wdkv = (const float*)d_in[1];
  const float* wuk = (const float*)d_in[2];
  const float* wuv = (const float*)d_in[3];
  const float* wuq = (const float*)d_in[4];
  const float* wo = (const float*)d_in[5];
  float* out = (float*)d_out;

  __bf16* ws = (__bf16*)d_ws;
  __bf16* x_bf = ws;                               // T*D
  __bf16* q = x_bf + (size_t)T_SEQ * DIMX;         // T*D (pre-scaled)
  __bf16* k = q + (size_t)T_SEQ * DIMX;            // T*D
  __bf16* vt = k + (size_t)T_SEQ * DIMX;           // D*T
  __bf16* ctx = vt + (size_t)T_SEQ * DIMX;         // T*D
  __bf16* ckv = ctx + (size_t)T_SEQ * DIMX;        // T*DLAT
  __bf16* wt_dkv = ckv + (size_t)T_SEQ * DLAT;     // DLAT x DIM
  __bf16* wt_uk = wt_dkv + (size_t)DLAT * DIMX;    // DIM x DLAT
  __bf16* wt_uv = wt_uk + (size_t)DIMX * DLAT;     // DIM x DLAT
  __bf16* wt_uq = wt_uv + (size_t)DIMX * DLAT;     // DIM x DIM
  __bf16* wt_o = wt_uq + (size_t)DIMX * DIMX;      // DIM x DIM

  dim3 blk(256);
  prep_kernel<<<dim3(2752), blk, 0, stream>>>(x, wdkv, wuk, wuv, wuq, wo, x_bf,
                                              wt_dkv, wt_uk, wt_uv, wt_uq, wt_o);
  gemm_a64<<<dim3(20, T_SEQ / 128), blk, 0, stream>>>(x_bf, wt_dkv, wt_uq,
                                                      ckv, q);
  gemm_kv128<<<dim3(16, T_SEQ / 128), blk, 0, stream>>>(ckv, wt_uk, wt_uv, k,
                                                        vt);
  mla_attn11<<<dim3(NH, 64), dim3(256), 0, stream>>>(q, k, vt, ctx);
  gemm_f64<<<dim3(DIMX / 64, T_SEQ / 128), blk, 0, stream>>>(ctx, wt_o, out);
}